// Round 7
// baseline (354.091 us; speedup 1.0000x reference)
//
#include <hip/hip_runtime.h>
#include <math.h>

static constexpr int Bn = 8;
static constexpr int Cn = 256;
static constexpr int Sn = 16384;   // 128*128

typedef __bf16 bf16x4 __attribute__((ext_vector_type(4)));
typedef __bf16 bf16x8 __attribute__((ext_vector_type(8)));
typedef float  f32x4  __attribute__((ext_vector_type(4)));

static constexpr int TILE   = 128;
static constexpr int KB     = 32;
static constexpr int KSPLIT = 16;
static constexpr int KSLICE = Sn / KSPLIT;  // 1024

// ---------------- shared LDS layout helpers ----------------
// Tile buffer: 128 rows x 32 bf16 (one K-chunk), zero pad, XOR chunk swizzle.
// Row = 64 B = 4 chunks of 16 B. Data chunk c of row r lives at slot c^(r&3).
__device__ __forceinline__ void split_store(__bf16* __restrict__ Hi, __bf16* __restrict__ Lo,
                                            int row, int kq, float4 v) {
  __bf16 h0 = (__bf16)v.x, h1 = (__bf16)v.y, h2 = (__bf16)v.z, h3 = (__bf16)v.w;
  int off = row * 32 + (((kq >> 1) ^ (row & 3)) << 3) + ((kq & 1) << 2);
  *(bf16x4*)&Hi[off] = (bf16x4){h0, h1, h2, h3};
  *(bf16x4*)&Lo[off] = (bf16x4){(__bf16)(v.x - (float)h0), (__bf16)(v.y - (float)h1),
                                (__bf16)(v.z - (float)h2), (__bf16)(v.w - (float)h3)};
}

__device__ __forceinline__ bf16x8 frag_ld(const __bf16* __restrict__ P, int row, int quad) {
  return *(const bf16x8*)&P[row * 32 + ((quad ^ (row & 3)) << 3)];
}

// LDS-only barrier: waits ds ops (cross-wave hazard) but lets global->register
// prefetch loads stay in flight across the barrier (the compiler inserts the
// data-dependence vmcnt wait at the consuming split_store). __syncthreads would
// drain vmcnt(0) here and kill the pipeline.
__device__ __forceinline__ void lds_barrier() {
  asm volatile("s_waitcnt lgkmcnt(0)" ::: "memory");
  __builtin_amdgcn_s_barrier();
}

__device__ __forceinline__ f32x4 mfma16(bf16x8 a, bf16x8 b, f32x4 c) {
  return __builtin_amdgcn_mfma_f32_16x16x32_bf16(a, b, c, 0, 0, 0);
}

// ---------------- gram helpers ----------------
__device__ __forceinline__ void gram_gload(const float* __restrict__ Abase,
                                           const float* __restrict__ Bbase,
                                           bool diag, int srow, int skq, int kc,
                                           float4 (&ar)[4], float4 (&br)[4]) {
#pragma unroll
  for (int it = 0; it < 4; it++)
    ar[it] = *(const float4*)(Abase + (size_t)(srow + it * 32) * Sn + kc + skq * 4);
  if (!diag) {
#pragma unroll
    for (int it = 0; it < 4; it++)
      br[it] = *(const float4*)(Bbase + (size_t)(srow + it * 32) * Sn + kc + skq * 4);
  }
}

__device__ __forceinline__ void gram_stage(__bf16* Ah, __bf16* Al, __bf16* Bh, __bf16* Bl,
                                           bool diag, int srow, int skq,
                                           const float4 (&ar)[4], const float4 (&br)[4]) {
#pragma unroll
  for (int it = 0; it < 4; it++) split_store(Ah, Al, srow + it * 32, skq, ar[it]);
  if (!diag) {
#pragma unroll
    for (int it = 0; it < 4; it++) split_store(Bh, Bl, srow + it * 32, skq, br[it]);
  }
}

__device__ __forceinline__ void tile_mfma(const __bf16* Ah, const __bf16* Al,
                                          const __bf16* PH, const __bf16* PL,
                                          int wr, int wc, int ln, int quad,
                                          f32x4 (&acc)[4][4]) {
  bf16x8 fah[4], fal[4];
#pragma unroll
  for (int i = 0; i < 4; i++) {
    int ar = wr * 64 + i * 16 + ln;
    fah[i] = frag_ld(Ah, ar, quad);
    fal[i] = frag_ld(Al, ar, quad);
  }
#pragma unroll
  for (int j = 0; j < 4; j++) {
    int br = wc * 64 + j * 16 + ln;
    bf16x8 fbh = frag_ld(PH, br, quad);
    bf16x8 fbl = frag_ld(PL, br, quad);
#pragma unroll
    for (int i = 0; i < 4; i++) {
      acc[i][j] = mfma16(fah[i], fbh, acc[i][j]);
      acc[i][j] = mfma16(fah[i], fbl, acc[i][j]);
      acc[i][j] = mfma16(fal[i], fbh, acc[i][j]);
    }
  }
}

// ---------------- Kernel 1: Gram partials, no atomics, 2-deep pipeline ------
// energy[b][c][d] = sum_s v[b,c,s] v[b,d,s]; symmetric -> 3 tiles (2 diag +
// off-diag with mirrored store). Block writes its k-slice partial to private
// slot P[kk][b][.][.]; softmax_reduce sums. K-loop: single LDS buffer, two
// lgkm-only barriers per chunk, global loads issued 2 chunks ahead.
__global__ __launch_bounds__(256, 2) void gram_part_kernel(const float* __restrict__ x,
                                                           float* __restrict__ P) {
  const int b    = blockIdx.z;
  const int tsel = blockIdx.y;            // 0,1 diag; 2 off-diag
  const int kk   = blockIdx.x;            // 0..15
  const int ti   = (tsel == 1) ? 1 : 0;
  const int tj   = (tsel == 0) ? 0 : 1;
  const bool diag = (tsel < 2);

  const float* vb    = x + (size_t)b * Cn * Sn;
  const float* Abase = vb + (size_t)(ti * TILE) * Sn + kk * KSLICE;
  const float* Bbase = vb + (size_t)(tj * TILE) * Sn + kk * KSLICE;

  __shared__ __align__(16) __bf16 Ah[TILE * 32];
  __shared__ __align__(16) __bf16 Al[TILE * 32];
  __shared__ __align__(16) __bf16 Bh[TILE * 32];
  __shared__ __align__(16) __bf16 Bl[TILE * 32];

  const int t    = threadIdx.x;
  const int lane = t & 63;
  const int wv   = t >> 6;
  const int wr   = wv >> 1;
  const int wc   = wv & 1;
  const int ln   = lane & 15;
  const int quad = lane >> 4;
  const int srow = t >> 3;
  const int skq  = t & 7;

  const __bf16* PH = diag ? Ah : Bh;
  const __bf16* PL = diag ? Al : Bl;

  // two named register sets (rule #20: static indexing only)
  float4 arA[4], brA[4], arB[4], brB[4];

  // prologue: chunk0 -> A-set -> LDS; chunk1 -> B-set (in flight)
  gram_gload(Abase, Bbase, diag, srow, skq, 0, arA, brA);
  gram_gload(Abase, Bbase, diag, srow, skq, KB, arB, brB);
  gram_stage(Ah, Al, Bh, Bl, diag, srow, skq, arA, brA);
  lds_barrier();

  f32x4 acc[4][4];
#pragma unroll
  for (int i = 0; i < 4; i++)
#pragma unroll
    for (int j = 0; j < 4; j++) acc[i][j] = (f32x4){0.f, 0.f, 0.f, 0.f};

  for (int kc = 0; kc < KSLICE; kc += 2 * KB) {
    // ---- even chunk kc: LDS holds kc; prefetch kc+2KB -> A; stage kc+KB from B
    if (kc + 2 * KB < KSLICE)
      gram_gload(Abase, Bbase, diag, srow, skq, kc + 2 * KB, arA, brA);
    tile_mfma(Ah, Al, PH, PL, wr, wc, ln, quad, acc);
    lds_barrier();                         // reads done -> safe to overwrite
    gram_stage(Ah, Al, Bh, Bl, diag, srow, skq, arB, brB);
    lds_barrier();                         // writes visible -> safe to read

    // ---- odd chunk kc+KB: prefetch kc+3KB -> B; stage kc+2KB from A
    const int c1 = kc + KB;
    if (c1 + 2 * KB < KSLICE)
      gram_gload(Abase, Bbase, diag, srow, skq, c1 + 2 * KB, arB, brB);
    tile_mfma(Ah, Al, PH, PL, wr, wc, ln, quad, acc);
    lds_barrier();
    if (c1 + KB < KSLICE)
      gram_stage(Ah, Al, Bh, Bl, diag, srow, skq, arA, brA);
    lds_barrier();
  }

  // epilogue: plain stores to private slot. C/D layout col=lane&15, row=quad*4+reg.
  float* Pb = P + ((size_t)kk * Bn + b) * (Cn * Cn);
#pragma unroll
  for (int i = 0; i < 4; i++)
#pragma unroll
    for (int j = 0; j < 4; j++) {
      int c0 = ti * TILE + wr * 64 + i * 16 + quad * 4;
      int d  = tj * TILE + wc * 64 + j * 16 + ln;
#pragma unroll
      for (int r = 0; r < 4; r++) {
        float v = acc[i][j][r];
        Pb[(size_t)(c0 + r) * Cn + d] = v;
        if (!diag) Pb[(size_t)d * Cn + (c0 + r)] = v;   // mirror (1,0) tile
      }
    }
}

// ---------------- Kernel 2: reduce partials + softmax, wave per row ----------
__global__ __launch_bounds__(256) void softmax_reduce_kernel(const float* __restrict__ P,
                                                             float* __restrict__ w) {
  const int wv   = threadIdx.x >> 6;
  const int lane = threadIdx.x & 63;
  const int row  = blockIdx.x * 4 + wv;     // b*Cn + c
  const size_t off = (size_t)row * Cn + lane * 4;

  float4 e = (float4){0.f, 0.f, 0.f, 0.f};
#pragma unroll
  for (int kk = 0; kk < KSPLIT; kk++) {
    float4 p = *(const float4*)&P[(size_t)kk * (Bn * Cn * Cn) + off];
    e.x += p.x; e.y += p.y; e.z += p.z; e.w += p.w;
  }

  float m = fminf(fminf(e.x, e.y), fminf(e.z, e.w));
#pragma unroll
  for (int o = 32; o > 0; o >>= 1) m = fminf(m, __shfl_xor(m, o));

  float4 p;
  p.x = expf(m - e.x); p.y = expf(m - e.y);
  p.z = expf(m - e.z); p.w = expf(m - e.w);
  float s = p.x + p.y + p.z + p.w;
#pragma unroll
  for (int o = 32; o > 0; o >>= 1) s += __shfl_xor(s, o);

  float inv = 1.f / s;
  p.x *= inv; p.y *= inv; p.z *= inv; p.w *= inv;
  *(float4*)&w[off] = p;
}

// ---------------- ygemm helpers ----------------
__device__ __forceinline__ void y_gload(const float* __restrict__ Wb,
                                        const float* __restrict__ Vb, int s0,
                                        int srow, int skq, int kc,
                                        float4 (&ar)[4], float (&br)[16]) {
#pragma unroll
  for (int it = 0; it < 4; it++)
    ar[it] = *(const float4*)(Wb + (size_t)(srow + it * 32) * Cn + kc + skq * 4);
#pragma unroll
  for (int it = 0; it < 4; it++) {
    const float* col = Vb + (size_t)(kc + skq * 4) * Sn + s0 + srow + it * 32;
    br[it * 4 + 0] = col[0];
    br[it * 4 + 1] = col[(size_t)Sn];
    br[it * 4 + 2] = col[(size_t)2 * Sn];
    br[it * 4 + 3] = col[(size_t)3 * Sn];
  }
}

__device__ __forceinline__ void y_stage(__bf16* Ah, __bf16* Al, __bf16* Bh, __bf16* Bl,
                                        int srow, int skq,
                                        const float4 (&ar)[4], const float (&br)[16]) {
#pragma unroll
  for (int it = 0; it < 4; it++) split_store(Ah, Al, srow + it * 32, skq, ar[it]);
#pragma unroll
  for (int it = 0; it < 4; it++) {
    float4 bv = make_float4(br[it * 4 + 0], br[it * 4 + 1],
                            br[it * 4 + 2], br[it * 4 + 3]);
    split_store(Bh, Bl, srow + it * 32, skq, bv);
  }
}

// ---------------- Kernel 3: y = w @ v, out = alpha*y + x, 2-deep pipeline ----
__global__ __launch_bounds__(256, 2) void ygemm_mfma_kernel(const float* __restrict__ w,
                                                            const float* __restrict__ x,
                                                            const float* __restrict__ alpha,
                                                            float* __restrict__ out) {
  const int b  = blockIdx.z;
  const int m0 = blockIdx.y * 128;
  const int s0 = blockIdx.x * 128;

  const float* Wb = w + ((size_t)b * Cn + m0) * Cn;
  const float* Vb = x + (size_t)b * Cn * Sn;

  __shared__ __align__(16) __bf16 Ah[128 * 32];
  __shared__ __align__(16) __bf16 Al[128 * 32];
  __shared__ __align__(16) __bf16 Bh[128 * 32];   // transposed: [s][k]
  __shared__ __align__(16) __bf16 Bl[128 * 32];

  const int t    = threadIdx.x;
  const int lane = t & 63;
  const int wv   = t >> 6;
  const int wr   = wv >> 1;
  const int wc   = wv & 1;
  const int ln   = lane & 15;
  const int quad = lane >> 4;
  const int srow = t >> 3;
  const int skq  = t & 7;

  float4 arA[4], arB[4];
  float  brA[16], brB[16];

  // prologue: chunk0 -> A-set -> LDS; chunk1 -> B-set (in flight)
  y_gload(Wb, Vb, s0, srow, skq, 0, arA, brA);
  y_gload(Wb, Vb, s0, srow, skq, KB, arB, brB);
  y_stage(Ah, Al, Bh, Bl, srow, skq, arA, brA);
  lds_barrier();

  f32x4 acc[4][4];
#pragma unroll
  for (int i = 0; i < 4; i++)
#pragma unroll
    for (int j = 0; j < 4; j++) acc[i][j] = (f32x4){0.f, 0.f, 0.f, 0.f};

  for (int kc = 0; kc < Cn; kc += 2 * KB) {
    // ---- even chunk kc
    if (kc + 2 * KB < Cn)
      y_gload(Wb, Vb, s0, srow, skq, kc + 2 * KB, arA, brA);
    tile_mfma(Ah, Al, Bh, Bl, wr, wc, ln, quad, acc);
    lds_barrier();
    y_stage(Ah, Al, Bh, Bl, srow, skq, arB, brB);
    lds_barrier();

    // ---- odd chunk kc+KB
    const int c1 = kc + KB;
    if (c1 + 2 * KB < Cn)
      y_gload(Wb, Vb, s0, srow, skq, c1 + 2 * KB, arB, brB);
    tile_mfma(Ah, Al, Bh, Bl, wr, wc, ln, quad, acc);
    lds_barrier();
    if (c1 + KB < Cn)
      y_stage(Ah, Al, Bh, Bl, srow, skq, arA, brA);
    lds_barrier();
  }

  // epilogue: fuse residual + alpha
  const float al = alpha[0];
#pragma unroll
  for (int i = 0; i < 4; i++)
#pragma unroll
    for (int j = 0; j < 4; j++) {
      int c = m0 + wr * 64 + i * 16 + quad * 4;
      int s = s0 + wc * 64 + j * 16 + ln;
      const float* xr = x   + ((size_t)b * Cn + c) * Sn + s;
      float*       op = out + ((size_t)b * Cn + c) * Sn + s;
#pragma unroll
      for (int r = 0; r < 4; r++)
        op[(size_t)r * Sn] = al * acc[i][j][r] + xr[(size_t)r * Sn];
    }
}

// ============ fallback (R3-measured atomic path, used if ws too small) ======
__global__ __launch_bounds__(256, 2) void gram_atomic_kernel(const float* __restrict__ x,
                                                             float* __restrict__ energy) {
  const int b    = blockIdx.z;
  const int tsel = blockIdx.y;
  const int kk   = blockIdx.x;
  const int ti   = (tsel == 1) ? 1 : 0;
  const int tj   = (tsel == 0) ? 0 : 1;
  const bool diag = (tsel < 2);

  const float* vb    = x + (size_t)b * Cn * Sn;
  const float* Abase = vb + (size_t)(ti * TILE) * Sn + kk * KSLICE;
  const float* Bbase = vb + (size_t)(tj * TILE) * Sn + kk * KSLICE;

  __shared__ __align__(16) __bf16 Ah[TILE * 32];
  __shared__ __align__(16) __bf16 Al[TILE * 32];
  __shared__ __align__(16) __bf16 Bh[TILE * 32];
  __shared__ __align__(16) __bf16 Bl[TILE * 32];

  const int t    = threadIdx.x;
  const int lane = t & 63;
  const int wv   = t >> 6;
  const int wr   = wv >> 1;
  const int wc   = wv & 1;
  const int ln   = lane & 15;
  const int quad = lane >> 4;
  const int srow = t >> 3;
  const int skq  = t & 7;

  float4 areg[4], breg[4];
#pragma unroll
  for (int it = 0; it < 4; it++)
    areg[it] = *(const float4*)(Abase + (size_t)(srow + it * 32) * Sn + skq * 4);
  if (!diag) {
#pragma unroll
    for (int it = 0; it < 4; it++)
      breg[it] = *(const float4*)(Bbase + (size_t)(srow + it * 32) * Sn + skq * 4);
  }

  f32x4 acc[4][4];
#pragma unroll
  for (int i = 0; i < 4; i++)
#pragma unroll
    for (int j = 0; j < 4; j++) acc[i][j] = (f32x4){0.f, 0.f, 0.f, 0.f};

  for (int kc = 0; kc < KSLICE; kc += KB) {
#pragma unroll
    for (int it = 0; it < 4; it++) split_store(Ah, Al, srow + it * 32, skq, areg[it]);
    if (!diag) {
#pragma unroll
      for (int it = 0; it < 4; it++) split_store(Bh, Bl, srow + it * 32, skq, breg[it]);
    }
    __syncthreads();

    const __bf16* PH = diag ? Ah : Bh;
    const __bf16* PL = diag ? Al : Bl;

    if (kc + KB < KSLICE) {
#pragma unroll
      for (int it = 0; it < 4; it++)
        areg[it] = *(const float4*)(Abase + (size_t)(srow + it * 32) * Sn + (kc + KB) + skq * 4);
      if (!diag) {
#pragma unroll
        for (int it = 0; it < 4; it++)
          breg[it] = *(const float4*)(Bbase + (size_t)(srow + it * 32) * Sn + (kc + KB) + skq * 4);
      }
    }

    tile_mfma(Ah, Al, PH, PL, wr, wc, ln, quad, acc);
    __syncthreads();
  }

  float* E = energy + (size_t)b * Cn * Cn;
#pragma unroll
  for (int i = 0; i < 4; i++)
#pragma unroll
    for (int j = 0; j < 4; j++) {
      int c0 = ti * TILE + wr * 64 + i * 16 + quad * 4;
      int d  = tj * TILE + wc * 64 + j * 16 + ln;
#pragma unroll
      for (int r = 0; r < 4; r++) {
        float v = acc[i][j][r];
        atomicAdd(&E[(size_t)(c0 + r) * Cn + d], v);
        if (tsel == 2) atomicAdd(&E[(size_t)d * Cn + (c0 + r)], v);
      }
    }
}

__global__ __launch_bounds__(256) void softmax_kernel(float* __restrict__ energy) {
  const int wv   = threadIdx.x >> 6;
  const int lane = threadIdx.x & 63;
  const int row  = blockIdx.x * 4 + wv;

  float4 e = *(const float4*)&energy[(size_t)row * Cn + lane * 4];
  float m = fminf(fminf(e.x, e.y), fminf(e.z, e.w));
#pragma unroll
  for (int o = 32; o > 0; o >>= 1) m = fminf(m, __shfl_xor(m, o));

  float4 p;
  p.x = expf(m - e.x); p.y = expf(m - e.y);
  p.z = expf(m - e.z); p.w = expf(m - e.w);
  float s = p.x + p.y + p.z + p.w;
#pragma unroll
  for (int o = 32; o > 0; o >>= 1) s += __shfl_xor(s, o);

  float inv = 1.f / s;
  p.x *= inv; p.y *= inv; p.z *= inv; p.w *= inv;
  *(float4*)&energy[(size_t)row * Cn + lane * 4] = p;
}

extern "C" void kernel_launch(void* const* d_in, const int* in_sizes, int n_in,
                              void* d_out, int out_size, void* d_ws, size_t ws_size,
                              hipStream_t stream) {
  const float* x     = (const float*)d_in[0];
  const float* alpha = (const float*)d_in[1];
  float*       out   = (float*)d_out;

  const size_t ecnt  = (size_t)Bn * Cn * Cn;            // 524288 floats (2 MB)
  const size_t pcnt  = (size_t)KSPLIT * ecnt;           // 32 MB of partials
  const size_t need  = (pcnt + ecnt) * sizeof(float);   // 34 MB

  dim3 g1(KSPLIT, 3, Bn);                               // 16 x 3 x 8 = 384 blocks
  dim3 g3(Sn / 128, Cn / 128, Bn);                      // 128 x 2 x 8 = 2048 blocks

  if (ws_size >= need) {
    float* P = (float*)d_ws;                            // [kk][b][c][d]
    float* w = (float*)d_ws + pcnt;                     // softmax output

    gram_part_kernel<<<g1, 256, 0, stream>>>(x, P);
    softmax_reduce_kernel<<<(Bn * Cn) / 4, 256, 0, stream>>>(P, w);
    ygemm_mfma_kernel<<<g3, 256, 0, stream>>>(w, x, alpha, out);
  } else {
    // fallback (atomic gram)
    float* energy = (float*)d_ws;
    hipMemsetAsync(energy, 0, ecnt * sizeof(float), stream);
    gram_atomic_kernel<<<g1, 256, 0, stream>>>(x, energy);
    softmax_kernel<<<(Bn * Cn) / 4, 256, 0, stream>>>(energy);
    ygemm_mfma_kernel<<<g3, 256, 0, stream>>>(energy, x, alpha, out);
  }
}